// Round 1
// baseline (642.387 us; speedup 1.0000x reference)
//
#include <hip/hip_runtime.h>

// HarmonicLowering: out[b, k*C+c, f, t] = w*x[b,c,i0,t] + (1-w)*x[b,c,i1,t]
//   prod = f*(k+1); i0 = prod>>2; w = 1 - (prod&3)/4; i1 = min(i0+1, F-1)
// Shapes: x (8,32,256,512) f32 -> out (8,128,256,512) f32.
// Memory-bound: 512 MiB write + ~128 MiB compulsory read.

constexpr int BATCH = 8;
constexpr int C     = 32;
constexpr int FREQ  = 256;
constexpr int TIME  = 512;
constexpr int T4    = TIME / 4;              // 128 float4 per row
constexpr int TOTAL4 = BATCH * 4 * C * FREQ * T4; // 2^25 float4 outputs

__global__ __launch_bounds__(256) void harmonic_lowering_kernel(
    const float4* __restrict__ x, float4* __restrict__ out)
{
    int id = blockIdx.x * 256 + threadIdx.x;   // < 2^25, fits int

    // Decode (b, k, c, f, tv) from flat float4 index; all dims are pow2.
    int tv   = id & (T4 - 1);
    int rest = id >> 7;          // / T4
    int f    = rest & (FREQ - 1);
    rest   >>= 8;                // / FREQ
    int c    = rest & (C - 1);
    rest   >>= 5;                // / C
    int k    = rest & 3;         // harmonic index, ks = k+1
    int b    = rest >> 2;

    int prod = f * (k + 1);
    int i0   = prod >> 2;
    int i1   = min(i0 + 1, FREQ - 1);
    float w  = 1.0f - (float)(prod & 3) * 0.25f;

    const float4* base = x + ((b * C + c) * FREQ) * T4;
    float4 g0 = base[i0 * T4 + tv];
    float4 g1 = base[i1 * T4 + tv];

    float4 o;
    o.x = w * g0.x + (1.0f - w) * g1.x;
    o.y = w * g0.y + (1.0f - w) * g1.y;
    o.z = w * g0.z + (1.0f - w) * g1.z;
    o.w = w * g0.w + (1.0f - w) * g1.w;

    out[id] = o;
}

extern "C" void kernel_launch(void* const* d_in, const int* in_sizes, int n_in,
                              void* d_out, int out_size, void* d_ws, size_t ws_size,
                              hipStream_t stream) {
    const float4* x  = (const float4*)d_in[0];
    float4* out      = (float4*)d_out;
    const int blocks = TOTAL4 / 256;  // 131072 blocks
    harmonic_lowering_kernel<<<blocks, 256, 0, stream>>>(x, out);
}